// Round 4
// baseline (328.937 us; speedup 1.0000x reference)
//
#include <hip/hip_runtime.h>
#include <math.h>

// Masked sparsemax, TWO rows per wave, rows fully in registers.
//
// R2 post-mortem: three different kernels all pinned at ~117-127 us and
// ~2.3 TB/s with VALU<=18%, HBM 28% -- memory-queueing bound with bursty
// one-shot waves, plus the output stream evicts the (almost-L3-resident)
// inputs. Fixes here:
//   1. 2 rows/wave: row B's 16 loads are issued BEFORE row A's max-reduction
//      and Michelot loop, so B's HBM latency hides under A's compute; the
//      fused dual Michelot loop runs two independent dependence chains that
//      fill each other's shuffle-latency shadows.
//   2. Non-temporal stores for out: the 134 MB write stream no longer
//      allocates in L3, so the 268 MB input set stays resident across
//      dispatches -> HBM fetch drops toward the overflow (~12 MB).
//      (R3 fix: __builtin_nontemporal_store needs a NATIVE vector type,
//      not HIP's float4 class -- use ext_vector_type(4).)
//
// Algorithm per row (unchanged from R2, verified): Newton/Michelot on
// f(theta)=sum(max(z-theta,0)), start theta = rowmax-1 (valid since p_max<=1),
// count C via per-slot __ballot+__popcll (wave-uniform, scalar pipe), only f
// needs the 6-step butterfly. Converges in ~3-4 iterations.

constexpr int D   = 2048;
constexpr int TPB = 256;             // 4 waves per block
constexpr int EPT = D / 64;          // 32 elements per lane
constexpr int CHK = EPT / 4;         // 8 float4 chunks per lane
constexpr int RPB = 2 * (TPB / 64);  // 8 rows per block (2 per wave)

typedef float nt_f4 __attribute__((ext_vector_type(4)));  // native vec for nt-store

__global__ __launch_bounds__(TPB, 4) void sparsemax_kernel(
    const float* __restrict__ x,
    const int*   __restrict__ mask,
    float*       __restrict__ out,
    int n_rows)
{
    const int wave = threadIdx.x >> 6;
    const int lane = threadIdx.x & 63;
    const int g    = blockIdx.x * (TPB / 64) + wave;
    const int rA   = g * 2;
    const int rB   = rA + 1;
    if (rA >= n_rows) return;            // wave-uniform; no barriers anywhere
    const bool hasB = (rB < n_rows);

    const size_t baseA = (size_t)rA * D;
    const size_t baseB = (size_t)rB * D;

    // ---- row A: 16 loads in flight, coalesced 1 KiB/chunk ----
    float4 xa[CHK]; int4 ma[CHK];
    #pragma unroll
    for (int c = 0; c < CHK; ++c) {
        const size_t off = baseA + (size_t)(c * 256 + lane * 4);
        xa[c] = *(const float4*)(x    + off);
        ma[c] = *(const int4*)  (mask + off);
    }
    float zA[EPT];
    #pragma unroll
    for (int c = 0; c < CHK; ++c) {
        zA[c * 4 + 0] = ma[c].x ? xa[c].x : -INFINITY;
        zA[c * 4 + 1] = ma[c].y ? xa[c].y : -INFINITY;
        zA[c * 4 + 2] = ma[c].z ? xa[c].z : -INFINITY;
        zA[c * 4 + 3] = ma[c].w ? xa[c].w : -INFINITY;
    }

    // ---- issue row B loads NOW; they fly under A's reductions ----
    float4 xb[CHK]; int4 mb[CHK];
    if (hasB) {
        #pragma unroll
        for (int c = 0; c < CHK; ++c) {
            const size_t off = baseB + (size_t)(c * 256 + lane * 4);
            xb[c] = *(const float4*)(x    + off);
            mb[c] = *(const int4*)  (mask + off);
        }
    }

    // ---- row A max (4 chains + butterfly) while B's loads are in flight ----
    float m0 = zA[0], m1 = zA[1], m2 = zA[2], m3 = zA[3];
    #pragma unroll
    for (int k = 4; k < EPT; k += 4) {
        m0 = fmaxf(m0, zA[k + 0]);
        m1 = fmaxf(m1, zA[k + 1]);
        m2 = fmaxf(m2, zA[k + 2]);
        m3 = fmaxf(m3, zA[k + 3]);
    }
    float gmaxA = fmaxf(fmaxf(m0, m1), fmaxf(m2, m3));
    #pragma unroll
    for (int off = 32; off > 0; off >>= 1)
        gmaxA = fmaxf(gmaxA, __shfl_xor(gmaxA, off, 64));

    // ---- convert row B, compute its max ----
    float zB[EPT];
    if (hasB) {
        #pragma unroll
        for (int c = 0; c < CHK; ++c) {
            zB[c * 4 + 0] = mb[c].x ? xb[c].x : -INFINITY;
            zB[c * 4 + 1] = mb[c].y ? xb[c].y : -INFINITY;
            zB[c * 4 + 2] = mb[c].z ? xb[c].z : -INFINITY;
            zB[c * 4 + 3] = mb[c].w ? xb[c].w : -INFINITY;
        }
    } else {
        #pragma unroll
        for (int k = 0; k < EPT; ++k) zB[k] = -INFINITY;
    }
    m0 = zB[0]; m1 = zB[1]; m2 = zB[2]; m3 = zB[3];
    #pragma unroll
    for (int k = 4; k < EPT; k += 4) {
        m0 = fmaxf(m0, zB[k + 0]);
        m1 = fmaxf(m1, zB[k + 1]);
        m2 = fmaxf(m2, zB[k + 2]);
        m3 = fmaxf(m3, zB[k + 3]);
    }
    float gmaxB = fmaxf(fmaxf(m0, m1), fmaxf(m2, m3));
    #pragma unroll
    for (int off = 32; off > 0; off >>= 1)
        gmaxB = fmaxf(gmaxB, __shfl_xor(gmaxB, off, 64));

    // ---- fused dual Michelot: two independent dep chains per iteration ----
    bool doneA = (gmaxA == -INFINITY);
    bool doneB = (gmaxB == -INFINITY);      // covers !hasB (zB all -inf)
    float thA = doneA ? INFINITY : gmaxA - 1.0f;
    float thB = doneB ? INFINITY : gmaxB - 1.0f;
    int pcA = -1, pcB = -1;

    for (int it = 0; it < 64 && !(doneA && doneB); ++it) {
        // f for both rows, 4 accumulator chains each (branchless; a finished
        // row's extra passes are cheap and harmless -- its theta is frozen)
        float a0 = 0.f, a1 = 0.f, a2 = 0.f, a3 = 0.f;
        float b0 = 0.f, b1 = 0.f, b2 = 0.f, b3 = 0.f;
        #pragma unroll
        for (int k = 0; k < EPT; k += 4) {
            a0 += fmaxf(zA[k + 0] - thA, 0.0f);
            a1 += fmaxf(zA[k + 1] - thA, 0.0f);
            a2 += fmaxf(zA[k + 2] - thA, 0.0f);
            a3 += fmaxf(zA[k + 3] - thA, 0.0f);
            b0 += fmaxf(zB[k + 0] - thB, 0.0f);
            b1 += fmaxf(zB[k + 1] - thB, 0.0f);
            b2 += fmaxf(zB[k + 2] - thB, 0.0f);
            b3 += fmaxf(zB[k + 3] - thB, 0.0f);
        }
        float fA = (a0 + a1) + (a2 + a3);
        float fB = (b0 + b1) + (b2 + b3);
        // counts: scalar-pipe popcount of ballots, wave-uniform result
        int CA = 0, CB = 0;
        #pragma unroll
        for (int k = 0; k < EPT; ++k) {
            CA += (int)__popcll(__ballot(zA[k] > thA));
            CB += (int)__popcll(__ballot(zB[k] > thB));
        }
        // dual interleaved butterflies (chains overlap in the ds pipe)
        #pragma unroll
        for (int off = 32; off > 0; off >>= 1) {
            fA += __shfl_xor(fA, off, 64);
            fB += __shfl_xor(fB, off, 64);
        }
        if (!doneA) {
            if (CA == 0 || CA == pcA) doneA = true;
            else { thA += (fA - 1.0f) / (float)CA; pcA = CA; }
        }
        if (!doneB) {
            if (CB == 0 || CB == pcB) doneB = true;
            else { thB += (fB - 1.0f) / (float)CB; pcB = CB; }
        }
    }

    // ---- epilogue: p = max(z - theta, 0); NON-TEMPORAL stores so the write
    // stream doesn't evict the (almost-L3-resident) input set ----
    #pragma unroll
    for (int c = 0; c < CHK; ++c) {
        const size_t off = baseA + (size_t)(c * 256 + lane * 4);
        nt_f4 o;
        o.x = fmaxf(zA[c * 4 + 0] - thA, 0.0f);
        o.y = fmaxf(zA[c * 4 + 1] - thA, 0.0f);
        o.z = fmaxf(zA[c * 4 + 2] - thA, 0.0f);
        o.w = fmaxf(zA[c * 4 + 3] - thA, 0.0f);
        __builtin_nontemporal_store(o, (nt_f4*)(out + off));
    }
    if (hasB) {
        #pragma unroll
        for (int c = 0; c < CHK; ++c) {
            const size_t off = baseB + (size_t)(c * 256 + lane * 4);
            nt_f4 o;
            o.x = fmaxf(zB[c * 4 + 0] - thB, 0.0f);
            o.y = fmaxf(zB[c * 4 + 1] - thB, 0.0f);
            o.z = fmaxf(zB[c * 4 + 2] - thB, 0.0f);
            o.w = fmaxf(zB[c * 4 + 3] - thB, 0.0f);
            __builtin_nontemporal_store(o, (nt_f4*)(out + off));
        }
    }
}

extern "C" void kernel_launch(void* const* d_in, const int* in_sizes, int n_in,
                              void* d_out, int out_size, void* d_ws, size_t ws_size,
                              hipStream_t stream) {
    const float* x    = (const float*)d_in[0];
    const int*   mask = (const int*)  d_in[1];
    float*       out  = (float*)d_out;
    const int n_rows = in_sizes[0] / D;
    const int blocks = (n_rows + RPB - 1) / RPB;
    sparsemax_kernel<<<blocks, TPB, 0, stream>>>(x, mask, out, n_rows);
}

// Round 5
// 296.114 us; speedup vs baseline: 1.1108x; 1.1108x over previous
//
#include <hip/hip_runtime.h>
#include <math.h>

// Masked sparsemax, one wave (64 lanes) per row, row in registers (32/lane).
//
// R4 post-mortem: nt-STORES increased HBM write traffic 20% on gfx950 and
// 2-rows/wave cut occupancy -- both reverted. All structures pin at an
// effective fabric rate of ~3.4 TB/s: the 268 MB input set thrashes the
// 256 MB L3 (write stream evicts input lines; ~50% hit rate), and the
// hit/miss interleave serves data far below the pure-HBM stream rate
// (copy ubench: 6.3 TB/s).
//
// This round: NON-TEMPORAL LOADS on x and mask. Each input byte is read
// exactly once per dispatch; nt prevents L3 allocation, converting the read
// side into pure HBM streams (like the copy bench) instead of a thrashing
// hit/miss mix. Stores stay regular float4 (nt-stores proven harmful in R4).
//
// Algorithm (verified R2): Newton/Michelot on f(theta)=sum(max(z-theta,0)),
// start theta = rowmax-1 (valid: p_max<=1 => theta* >= max-1), count C via
// per-slot __ballot+__popcll (wave-uniform, scalar pipe), only f needs the
// 6-step butterfly. ~3-4 iterations.

constexpr int D    = 2048;
constexpr int WPB  = 4;              // waves (= rows) per block
constexpr int TPB  = WPB * 64;       // 256 threads
constexpr int EPT  = D / 64;         // 32 elements per lane
constexpr int CHK  = EPT / 4;        // 8 float4 chunks per lane

typedef float f4 __attribute__((ext_vector_type(4)));  // native vecs for nt builtins
typedef int   i4 __attribute__((ext_vector_type(4)));

__global__ __launch_bounds__(TPB) void sparsemax_kernel(
    const float* __restrict__ x,
    const int*   __restrict__ mask,
    float*       __restrict__ out,
    int n_rows)
{
    const int wave = threadIdx.x >> 6;
    const int lane = threadIdx.x & 63;
    const int row  = blockIdx.x * WPB + wave;
    if (row >= n_rows) return;       // wave-uniform; no barriers anywhere

    const size_t rbase = (size_t)row * D;

    // Coalesced nt loads: per chunk the wave reads 1 KiB contiguous from x
    // and from mask; nt -> no L3 allocation, pure streaming.
    float z[EPT];
    #pragma unroll
    for (int c = 0; c < CHK; ++c) {
        const size_t off = rbase + (size_t)(c * 256 + lane * 4);
        const f4 a = __builtin_nontemporal_load((const f4*)(x    + off));
        const i4 m = __builtin_nontemporal_load((const i4*)(mask + off));
        z[c * 4 + 0] = m.x ? a.x : -INFINITY;
        z[c * 4 + 1] = m.y ? a.y : -INFINITY;
        z[c * 4 + 2] = m.z ? a.z : -INFINITY;
        z[c * 4 + 3] = m.w ? a.w : -INFINITY;
    }

    // Row max: 4 independent partial chains, then butterfly.
    float m0 = z[0], m1 = z[1], m2 = z[2], m3 = z[3];
    #pragma unroll
    for (int k = 4; k < EPT; k += 4) {
        m0 = fmaxf(m0, z[k + 0]);
        m1 = fmaxf(m1, z[k + 1]);
        m2 = fmaxf(m2, z[k + 2]);
        m3 = fmaxf(m3, z[k + 3]);
    }
    float gmax = fmaxf(fmaxf(m0, m1), fmaxf(m2, m3));
    #pragma unroll
    for (int off = 32; off > 0; off >>= 1)
        gmax = fmaxf(gmax, __shfl_xor(gmax, off, 64));

    float theta;
    if (gmax == -INFINITY) {
        theta = INFINITY;            // all-masked row -> all zeros
    } else {
        theta = gmax - 1.0f;         // valid Michelot start: theta* >= max-1
        int prevC = -1;
        for (int it = 0; it < 64; ++it) {
            // f(theta): branchless, 4 accumulator chains.
            float f0 = 0.0f, f1 = 0.0f, f2 = 0.0f, f3 = 0.0f;
            #pragma unroll
            for (int k = 0; k < EPT; k += 4) {
                f0 += fmaxf(z[k + 0] - theta, 0.0f);
                f1 += fmaxf(z[k + 1] - theta, 0.0f);
                f2 += fmaxf(z[k + 2] - theta, 0.0f);
                f3 += fmaxf(z[k + 3] - theta, 0.0f);
            }
            float f = (f0 + f1) + (f2 + f3);
            // C(theta): scalar-pipe popcount of ballots; wave-uniform result.
            int C = 0;
            #pragma unroll
            for (int k = 0; k < EPT; ++k)
                C += (int)__popcll(__ballot(z[k] > theta));
            // only f needs the cross-lane butterfly
            #pragma unroll
            for (int off = 32; off > 0; off >>= 1)
                f += __shfl_xor(f, off, 64);

            if (C == 0) break;       // defensive (cannot happen: z_max > theta*)
            if (C == prevC) break;   // set stable -> theta already exact
            theta += (f - 1.0f) / (float)C;
            prevC = C;
        }
    }

    // p = max(z - theta, 0); masked lanes (z=-inf) give exactly 0, including
    // the all-masked case. Regular cached stores (nt-stores hurt on gfx950).
    #pragma unroll
    for (int c = 0; c < CHK; ++c) {
        const size_t off = rbase + (size_t)(c * 256 + lane * 4);
        float4 o;
        o.x = fmaxf(z[c * 4 + 0] - theta, 0.0f);
        o.y = fmaxf(z[c * 4 + 1] - theta, 0.0f);
        o.z = fmaxf(z[c * 4 + 2] - theta, 0.0f);
        o.w = fmaxf(z[c * 4 + 3] - theta, 0.0f);
        *(float4*)(out + off) = o;
    }
}

extern "C" void kernel_launch(void* const* d_in, const int* in_sizes, int n_in,
                              void* d_out, int out_size, void* d_ws, size_t ws_size,
                              hipStream_t stream) {
    const float* x    = (const float*)d_in[0];
    const int*   mask = (const int*)  d_in[1];
    float*       out  = (float*)d_out;
    const int n_rows = in_sizes[0] / D;
    const int blocks = (n_rows + WPB - 1) / WPB;
    sparsemax_kernel<<<blocks, TPB, 0, stream>>>(x, mask, out, n_rows);
}